// Round 1
// baseline (63.384 us; speedup 1.0000x reference)
//
#include <hip/hip_runtime.h>
#include <cmath>

#define H 1024
#define V 50257
#define L 512

__device__ __forceinline__ float wred_sum(float v) {
#pragma unroll
    for (int o = 32; o > 0; o >>= 1) v += __shfl_xor(v, o, 64);
    return v;
}
__device__ __forceinline__ float wred_max(float v) {
#pragma unroll
    for (int o = 32; o > 0; o >>= 1) v = fmaxf(v, __shfl_xor(v, o, 64));
    return v;
}
__device__ __forceinline__ float dot4(float4 a, float4 b) {
    return a.x * b.x + a.y * b.y + a.z * b.z + a.w * b.w;
}

// K1: attn_logits[l] = [embedded, h] . W_attn[l,:] + b_attn[l]
__global__ void k_attn_logits(const int* __restrict__ tok,
                              const float* __restrict__ hid,
                              const float* __restrict__ emb,
                              const float* __restrict__ Wa,
                              const float* __restrict__ ba,
                              float* __restrict__ lg) {
    const int l = blockIdx.x;       // [0, 512)
    const int t = threadIdx.x;      // 256
    const float4* wr = (const float4*)(Wa + (size_t)l * 2048);
    const float4* e4 = (const float4*)(emb + (size_t)tok[0] * H);
    const float4* h4 = (const float4*)hid;
    float acc = 0.f;
#pragma unroll
    for (int i = 0; i < 2; ++i) {
        int f = t + i * 256;        // [0, 512) float4 index
        float4 w = wr[f];
        float4 s = (f < 256) ? e4[f] : h4[f - 256];
        acc += dot4(w, s);
    }
    __shared__ float sm[4];
    int lane = t & 63, wv = t >> 6;
    acc = wred_sum(acc);
    if (lane == 0) sm[wv] = acc;
    __syncthreads();
    if (t == 0) lg[l] = sm[0] + sm[1] + sm[2] + sm[3] + ba[l];
}

// K2: softmax over 512 logits -> attn_weights (to d_out); also zero aa accumulator
__global__ void k_softmax(const float* __restrict__ lg,
                          float* __restrict__ wout,
                          float* __restrict__ aa) {
    const int t = threadIdx.x;      // 512
    const int lane = t & 63, wv = t >> 6;
    __shared__ float sm[8];
    __shared__ float bc;
    float v = lg[t];
    float m = wred_max(v);
    if (lane == 0) sm[wv] = m;
    __syncthreads();
    if (t == 0) {
        float M = sm[0];
#pragma unroll
        for (int i = 1; i < 8; ++i) M = fmaxf(M, sm[i]);
        bc = M;
    }
    __syncthreads();
    const float M = bc;
    float e = expf(v - M);
    float s = wred_sum(e);
    __syncthreads();
    if (lane == 0) sm[wv] = s;
    __syncthreads();
    if (t == 0) {
        float S = 0.f;
#pragma unroll
        for (int i = 0; i < 8; ++i) S += sm[i];
        bc = S;
    }
    __syncthreads();
    wout[t] = e / bc;
    // zero the attn_applied accumulator for K3's atomics
    aa[t] = 0.f;
    aa[t + 512] = 0.f;
}

// K3: attn_applied[c] = sum_l w[l] * enc[l, c]   (partial over 32 rows, atomicAdd)
__global__ void k_attn_apply(const float* __restrict__ w,
                             const float* __restrict__ enc,
                             float* __restrict__ aa) {
    const int c = blockIdx.x * 256 + threadIdx.x;  // grid.x = 4
    const int l0 = blockIdx.y * 32;                // grid.y = 16
    float acc = 0.f;
#pragma unroll 8
    for (int l = l0; l < l0 + 32; ++l) acc += w[l] * enc[(size_t)l * H + c];
    atomicAdd(&aa[c], acc);
}

// K4: x[j] = relu([embedded, attn_applied] . W_comb[j,:] + b_comb[j])
__global__ void k_comb(const int* __restrict__ tok,
                       const float* __restrict__ emb,
                       const float* __restrict__ aa,
                       const float* __restrict__ Wc,
                       const float* __restrict__ bc_,
                       float* __restrict__ xv) {
    const int j = blockIdx.x;       // 1024
    const int t = threadIdx.x;      // 256
    const float4* wr = (const float4*)(Wc + (size_t)j * 2048);
    const float4* e4 = (const float4*)(emb + (size_t)tok[0] * H);
    const float4* a4 = (const float4*)aa;
    float acc = 0.f;
#pragma unroll
    for (int i = 0; i < 2; ++i) {
        int f = t + i * 256;
        float4 w = wr[f];
        float4 s = (f < 256) ? e4[f] : a4[f - 256];
        acc += dot4(w, s);
    }
    __shared__ float sm[4];
    int lane = t & 63, wv = t >> 6;
    acc = wred_sum(acc);
    if (lane == 0) sm[wv] = acc;
    __syncthreads();
    if (t == 0) xv[j] = fmaxf(sm[0] + sm[1] + sm[2] + sm[3] + bc_[j], 0.f);
}

// K5a: gi[j] = x . W_ih[j,:] + b_ih[j];  gh[j] = h . W_hh[j,:] + b_hh[j]
__global__ void k_gates(const float* __restrict__ xv,
                        const float* __restrict__ hid,
                        const float* __restrict__ Wih,
                        const float* __restrict__ Whh,
                        const float* __restrict__ bih,
                        const float* __restrict__ bhh,
                        float* __restrict__ gi,
                        float* __restrict__ gh) {
    const int j = blockIdx.x;       // 3072
    const int t = threadIdx.x;      // 256
    const float4* wi = (const float4*)(Wih + (size_t)j * H);
    const float4* wh = (const float4*)(Whh + (size_t)j * H);
    const float4* x4 = (const float4*)xv;
    const float4* h4 = (const float4*)hid;
    float a1 = dot4(wi[t], x4[t]);
    float a2 = dot4(wh[t], h4[t]);
    __shared__ float smA[4], smB[4];
    int lane = t & 63, wv = t >> 6;
    a1 = wred_sum(a1);
    a2 = wred_sum(a2);
    if (lane == 0) { smA[wv] = a1; smB[wv] = a2; }
    __syncthreads();
    if (t == 0) {
        gi[j] = smA[0] + smA[1] + smA[2] + smA[3] + bih[j];
        gh[j] = smB[0] + smB[1] + smB[2] + smB[3] + bhh[j];
    }
}

// K5b: GRU combine -> h_new (to d_out and aligned ws copy)
__global__ void k_gru(const float* __restrict__ gi,
                      const float* __restrict__ gh,
                      const float* __restrict__ hid,
                      float* __restrict__ hnew_out,
                      float* __restrict__ hnew_ws) {
    const int j = blockIdx.x * 256 + threadIdx.x;  // grid 4
    float r = 1.f / (1.f + expf(-(gi[j] + gh[j])));
    float z = 1.f / (1.f + expf(-(gi[H + j] + gh[H + j])));
    float n = tanhf(gi[2 * H + j] + r * gh[2 * H + j]);
    float hn = (1.f - z) * n + z * hid[j];
    hnew_out[j] = hn;
    hnew_ws[j] = hn;
}

// K6: logits[v] = h_new . W_out[v,:] + b_out[v]   (one wave per row, 4 rows/block)
__global__ void k_out_gemv(const float* __restrict__ hn,
                           const float* __restrict__ Wo,
                           const float* __restrict__ bo,
                           float* __restrict__ logits) {
    const int lane = threadIdx.x & 63, wv = threadIdx.x >> 6;
    const int v = blockIdx.x * 4 + wv;
    if (v >= V) return;
    const float4* wr = (const float4*)(Wo + (size_t)v * H);
    const float4* h4 = (const float4*)hn;
    float acc = 0.f;
#pragma unroll
    for (int i = 0; i < 4; ++i) {
        int f = i * 64 + lane;      // [0, 256) float4 index
        acc += dot4(wr[f], h4[f]);
    }
    acc = wred_sum(acc);
    if (lane == 0) logits[v] = acc + bo[v];
}

// K7a: partial max over 64 chunks of logits; also zero S for K7b's atomics
__global__ void k_pmax(const float* __restrict__ logits,
                       float* __restrict__ pmax,
                       float* __restrict__ S) {
    const int CH = (V + 63) / 64;   // 786
    const int b = blockIdx.x, t = threadIdx.x;  // 64 blocks x 256
    const int s = b * CH, e = min(s + CH, V);
    float m = -INFINITY;
    for (int i = s + t; i < e; i += 256) m = fmaxf(m, logits[i]);
    __shared__ float sm[4];
    int lane = t & 63, wv = t >> 6;
    m = wred_max(m);
    if (lane == 0) sm[wv] = m;
    __syncthreads();
    if (t == 0) {
        pmax[b] = fmaxf(fmaxf(sm[0], sm[1]), fmaxf(sm[2], sm[3]));
        if (b == 0) S[0] = 0.f;
    }
}

// K7b: global M from partials (recomputed per block), partial exp-sum, atomicAdd S
__global__ void k_expsum(const float* __restrict__ logits,
                         const float* __restrict__ pmax,
                         float* __restrict__ S,
                         float* __restrict__ Mout) {
    float M = -INFINITY;
#pragma unroll
    for (int i = 0; i < 64; ++i) M = fmaxf(M, pmax[i]);
    const int CH = (V + 63) / 64;
    const int b = blockIdx.x, t = threadIdx.x;
    const int s = b * CH, e = min(s + CH, V);
    float acc = 0.f;
    for (int i = s + t; i < e; i += 256) acc += expf(logits[i] - M);
    __shared__ float sm[4];
    int lane = t & 63, wv = t >> 6;
    acc = wred_sum(acc);
    if (lane == 0) sm[wv] = acc;
    __syncthreads();
    if (t == 0) {
        atomicAdd(S, sm[0] + sm[1] + sm[2] + sm[3]);
        if (b == 0) Mout[0] = M;
    }
}

// K8: in-place finalize: out[v] = logits[v] - M - log(S)
__global__ void k_logsm(float* __restrict__ out,
                        const float* __restrict__ S,
                        const float* __restrict__ M) {
    const int v = blockIdx.x * 256 + threadIdx.x;
    if (v < V) out[v] = out[v] - M[0] - logf(S[0]);
}

extern "C" void kernel_launch(void* const* d_in, const int* in_sizes, int n_in,
                              void* d_out, int out_size, void* d_ws, size_t ws_size,
                              hipStream_t stream) {
    const int*   tok = (const int*)d_in[0];
    const float* hid = (const float*)d_in[1];
    const float* enc = (const float*)d_in[2];
    const float* emb = (const float*)d_in[3];
    const float* Wa  = (const float*)d_in[4];
    const float* ba  = (const float*)d_in[5];
    const float* Wc  = (const float*)d_in[6];
    const float* bc  = (const float*)d_in[7];
    const float* Wih = (const float*)d_in[8];
    const float* Whh = (const float*)d_in[9];
    const float* bih = (const float*)d_in[10];
    const float* bhh = (const float*)d_in[11];
    const float* Wo  = (const float*)d_in[12];
    const float* bo  = (const float*)d_in[13];

    float* out = (float*)d_out;   // [V | H | L]
    float* ws  = (float*)d_ws;
    float* wlog = ws;             // 512   attn logits
    float* aa   = ws + 512;       // 1024  attn_applied (16B aligned)
    float* xv   = ws + 1536;      // 1024  x
    float* gi   = ws + 2560;      // 3072
    float* gh   = ws + 5632;      // 3072
    float* hn   = ws + 8704;      // 1024  h_new copy (16B aligned)
    float* pmax = ws + 9728;      // 64
    float* S    = ws + 9792;      // 1
    float* M    = ws + 9796;      // 1

    float* out_logits = out;          // V
    float* out_hnew   = out + V;      // H
    float* out_attnw  = out + V + H;  // L

    k_attn_logits<<<L, 256, 0, stream>>>(tok, hid, emb, Wa, ba, wlog);
    k_softmax<<<1, 512, 0, stream>>>(wlog, out_attnw, aa);
    k_attn_apply<<<dim3(4, 16), 256, 0, stream>>>(out_attnw, enc, aa);
    k_comb<<<H, 256, 0, stream>>>(tok, emb, aa, Wc, bc, xv);
    k_gates<<<3 * H, 256, 0, stream>>>(xv, hid, Wih, Whh, bih, bhh, gi, gh);
    k_gru<<<4, 256, 0, stream>>>(gi, gh, hid, out_hnew, hn);
    k_out_gemv<<<(V + 3) / 4, 256, 0, stream>>>(hn, Wo, bo, out_logits);
    k_pmax<<<64, 256, 0, stream>>>(out_logits, pmax, S);
    k_expsum<<<64, 256, 0, stream>>>(out_logits, pmax, S, M);
    k_logsm<<<(V + 255) / 256, 256, 0, stream>>>(out_logits, S, M);
}

// Round 2
// 58.448 us; speedup vs baseline: 1.0845x; 1.0845x over previous
//
#include <hip/hip_runtime.h>
#include <cmath>

#define H 1024
#define V 50257
#define L 512
#define NB5 1571   // (V + 31) / 32  blocks for the out-GEMV

__device__ __forceinline__ float wred_sum(float v) {
#pragma unroll
    for (int o = 32; o > 0; o >>= 1) v += __shfl_xor(v, o, 64);
    return v;
}
__device__ __forceinline__ float wred_max(float v) {
#pragma unroll
    for (int o = 32; o > 0; o >>= 1) v = fmaxf(v, __shfl_xor(v, o, 64));
    return v;
}
__device__ __forceinline__ float dot4(float4 a, float4 b) {
    return a.x * b.x + a.y * b.y + a.z * b.z + a.w * b.w;
}
// online logsumexp pair merge
__device__ __forceinline__ void ms_merge(float& m, float& s, float m2, float s2) {
    float M = fmaxf(m, m2);
    if (M == -INFINITY) { m = M; s = 0.f; return; }
    s = s * expf(m - M) + s2 * expf(m2 - M);
    m = M;
}

// K1: horizontal fusion of two independent jobs:
//   blocks [0,512):    attn_logits[l] = [embedded, h] . W_attn[l,:] + b_attn[l]
//   blocks [512,1280): gh[j] = h . W_hh[j,:] + b_hh[j]   (4 rows/block, wave-per-row)
//   block 512 also zeroes the attn_applied accumulator.
__global__ void k_phase1(const int* __restrict__ tok,
                         const float* __restrict__ hid,
                         const float* __restrict__ emb,
                         const float* __restrict__ Wa,
                         const float* __restrict__ ba,
                         const float* __restrict__ Whh,
                         const float* __restrict__ bhh,
                         float* __restrict__ lg,
                         float* __restrict__ gh,
                         float* __restrict__ aa) {
    const int t = threadIdx.x;
    const int lane = t & 63, wv = t >> 6;
    if (blockIdx.x < 512) {
        const int l = blockIdx.x;
        const float4* wr = (const float4*)(Wa + (size_t)l * 2048);
        const float4* e4 = (const float4*)(emb + (size_t)tok[0] * H);
        const float4* h4 = (const float4*)hid;
        float acc = 0.f;
#pragma unroll
        for (int i = 0; i < 2; ++i) {
            int f = t + i * 256;
            float4 w = wr[f];
            float4 s = (f < 256) ? e4[f] : h4[f - 256];
            acc += dot4(w, s);
        }
        __shared__ float sm[4];
        acc = wred_sum(acc);
        if (lane == 0) sm[wv] = acc;
        __syncthreads();
        if (t == 0) lg[l] = sm[0] + sm[1] + sm[2] + sm[3] + ba[l];
    } else {
        const int j = (blockIdx.x - 512) * 4 + wv;
        const float4* wh = (const float4*)(Whh + (size_t)j * H);
        const float4* h4 = (const float4*)hid;
        float acc = 0.f;
#pragma unroll
        for (int k = 0; k < 4; ++k) {
            int f = 64 * k + lane;
            acc += dot4(wh[f], h4[f]);
        }
        acc = wred_sum(acc);
        if (lane == 0) gh[j] = acc + bhh[j];
        if (blockIdx.x == 512) {
            aa[t] = 0.f; aa[t + 256] = 0.f; aa[t + 512] = 0.f; aa[t + 768] = 0.f;
        }
    }
}

// K2: softmax recomputed redundantly per block (2KB from L2) + attn_apply partial.
//   32 blocks, block b handles enc rows [16b, 16b+16); atomicAdd into aa.
//   Block 0 writes attn_weights to d_out.
__global__ void k_attn(const float* __restrict__ lg,
                       const float* __restrict__ enc,
                       float* __restrict__ wout,
                       float* __restrict__ aa) {
    const int t = threadIdx.x;
    const int lane = t & 63, wv = t >> 6;
    __shared__ float red[4];
    __shared__ float swL[512];
    float v0 = lg[t], v1 = lg[t + 256];
    float m = wred_max(fmaxf(v0, v1));
    if (lane == 0) red[wv] = m;
    __syncthreads();
    const float M = fmaxf(fmaxf(red[0], red[1]), fmaxf(red[2], red[3]));
    float e0 = expf(v0 - M), e1 = expf(v1 - M);
    float sl = wred_sum(e0 + e1);
    __syncthreads();
    if (lane == 0) red[wv] = sl;
    __syncthreads();
    const float S = red[0] + red[1] + red[2] + red[3];
    swL[t] = e0 / S;
    swL[t + 256] = e1 / S;
    __syncthreads();
    if (blockIdx.x == 0) { wout[t] = swL[t]; wout[t + 256] = swL[t + 256]; }
    const int l0 = blockIdx.x * 16;
    float a0 = 0.f, a1 = 0.f, a2 = 0.f, a3 = 0.f;
#pragma unroll 4
    for (int l = l0; l < l0 + 16; ++l) {
        const float w = swL[l];
        const float* er = enc + (size_t)l * H;
        a0 += w * er[t];
        a1 += w * er[t + 256];
        a2 += w * er[t + 512];
        a3 += w * er[t + 768];
    }
    atomicAdd(&aa[t], a0);
    atomicAdd(&aa[t + 256], a1);
    atomicAdd(&aa[t + 512], a2);
    atomicAdd(&aa[t + 768], a3);
}

// K3: x[j] = relu([embedded, attn_applied] . W_comb[j,:] + b_comb[j]); wave-per-row.
__global__ void k_comb(const int* __restrict__ tok,
                       const float* __restrict__ emb,
                       const float* __restrict__ aa,
                       const float* __restrict__ Wc,
                       const float* __restrict__ bcb,
                       float* __restrict__ xv) {
    const int lane = threadIdx.x & 63, wv = threadIdx.x >> 6;
    const int j = blockIdx.x * 4 + wv;   // grid 256
    const float4* wr = (const float4*)(Wc + (size_t)j * 2048);
    const float4* e4 = (const float4*)(emb + (size_t)tok[0] * H);
    const float4* a4 = (const float4*)aa;
    float acc = 0.f;
#pragma unroll
    for (int k = 0; k < 8; ++k) {
        int f = 64 * k + lane;
        float4 s = (k < 4) ? e4[f] : a4[f - 256];
        acc += dot4(wr[f], s);
    }
    acc = wred_sum(acc);
    if (lane == 0) xv[j] = fmaxf(acc + bcb[j], 0.f);
}

// K4: per-j fused gates+GRU. Wave computes gi_r/gi_z/gi_n for its j, then applies
//     the GRU pointwise with the precomputed gh. Writes h_new to d_out and ws.
__global__ void k_gates_gru(const float* __restrict__ xv,
                            const float* __restrict__ hid,
                            const float* __restrict__ Wih,
                            const float* __restrict__ bih,
                            const float* __restrict__ gh,
                            float* __restrict__ hn_out,
                            float* __restrict__ hn_ws) {
    const int lane = threadIdx.x & 63, wv = threadIdx.x >> 6;
    const int j = blockIdx.x * 4 + wv;   // grid 256
    const float4* x4 = (const float4*)xv;
    float4 xreg[4];
#pragma unroll
    for (int k = 0; k < 4; ++k) xreg[k] = x4[64 * k + lane];
    float g[3];
#pragma unroll
    for (int p = 0; p < 3; ++p) {
        const float4* wr = (const float4*)(Wih + (size_t)(j + p * H) * H);
        float acc = 0.f;
#pragma unroll
        for (int k = 0; k < 4; ++k) acc += dot4(wr[64 * k + lane], xreg[k]);
        g[p] = wred_sum(acc) + bih[j + p * H];
    }
    if (lane == 0) {
        float r = 1.f / (1.f + expf(-(g[0] + gh[j])));
        float z = 1.f / (1.f + expf(-(g[1] + gh[j + H])));
        float n = tanhf(g[2] + r * gh[j + 2 * H]);
        float hv = (1.f - z) * n + z * hid[j];
        hn_out[j] = hv;
        hn_ws[j] = hv;
    }
}

// K5: logits[v] = h_new . W_out[v,:] + b_out[v]; wave-per-row x 8 rows,
//     with online (max, sumexp) partial per block for the log_softmax.
__global__ void k_out_gemv(const float* __restrict__ hn,
                           const float* __restrict__ Wo,
                           const float* __restrict__ bo,
                           float* __restrict__ logits,
                           float* __restrict__ pm,
                           float* __restrict__ ps) {
    const int lane = threadIdx.x & 63, wv = threadIdx.x >> 6;
    const int b = blockIdx.x;
    const float4* h4 = (const float4*)hn;
    float4 hreg[4];
#pragma unroll
    for (int k = 0; k < 4; ++k) hreg[k] = h4[64 * k + lane];
    float m = -INFINITY, s = 0.f;
#pragma unroll
    for (int i = 0; i < 8; ++i) {
        const int v = b * 32 + wv * 8 + i;
        if (v < V) {
            const float4* wr = (const float4*)(Wo + (size_t)v * H);
            float acc = 0.f;
#pragma unroll
            for (int k = 0; k < 4; ++k) acc += dot4(wr[64 * k + lane], hreg[k]);
            acc = wred_sum(acc);
            const float logit = acc + bo[v];
            if (lane == 0) logits[v] = logit;
            const float M = fmaxf(m, logit);
            s = s * expf(m - M) + expf(logit - M);
            m = M;
        }
    }
    __shared__ float smm[4], sms[4];
    if (lane == 0) { smm[wv] = m; sms[wv] = s; }
    __syncthreads();
    if (threadIdx.x == 0) {
        float M = smm[0], S = sms[0];
#pragma unroll
        for (int i = 1; i < 4; ++i) ms_merge(M, S, smm[i], sms[i]);
        pm[b] = M; ps[b] = S;
    }
}

// K6: each block redundantly reduces the 1571 (m,s) partials (12.5KB, L2-hot)
//     to C = M + log(S), then finalizes its chunk: out[v] -= C.
__global__ void k_finalize(float* __restrict__ out,
                           const float* __restrict__ pm,
                           const float* __restrict__ ps) {
    const int t = threadIdx.x;
    const int lane = t & 63, wv = t >> 6;
    float m = -INFINITY, s = 0.f;
    for (int i = t; i < NB5; i += 256) ms_merge(m, s, pm[i], ps[i]);
#pragma unroll
    for (int o = 32; o > 0; o >>= 1) {
        float m2 = __shfl_xor(m, o, 64);
        float s2 = __shfl_xor(s, o, 64);
        ms_merge(m, s, m2, s2);
    }
    __shared__ float smm[4], sms[4];
    __shared__ float Cs;
    if (lane == 0) { smm[wv] = m; sms[wv] = s; }
    __syncthreads();
    if (t == 0) {
        float M = smm[0], S = sms[0];
#pragma unroll
        for (int i = 1; i < 4; ++i) ms_merge(M, S, smm[i], sms[i]);
        Cs = M + logf(S);
    }
    __syncthreads();
    const float C = Cs;
    const int v = blockIdx.x * 256 + t;
    if (v < V) out[v] -= C;
}

extern "C" void kernel_launch(void* const* d_in, const int* in_sizes, int n_in,
                              void* d_out, int out_size, void* d_ws, size_t ws_size,
                              hipStream_t stream) {
    const int*   tok = (const int*)d_in[0];
    const float* hid = (const float*)d_in[1];
    const float* enc = (const float*)d_in[2];
    const float* emb = (const float*)d_in[3];
    const float* Wa  = (const float*)d_in[4];
    const float* ba  = (const float*)d_in[5];
    const float* Wc  = (const float*)d_in[6];
    const float* bc  = (const float*)d_in[7];
    const float* Wih = (const float*)d_in[8];
    const float* Whh = (const float*)d_in[9];
    const float* bih = (const float*)d_in[10];
    const float* bhh = (const float*)d_in[11];
    const float* Wo  = (const float*)d_in[12];
    const float* bo  = (const float*)d_in[13];

    float* out = (float*)d_out;   // [V | H | L]
    float* ws  = (float*)d_ws;
    float* wlog = ws;             // 512   attn logits
    float* aa   = ws + 512;       // 1024  attn_applied (16B aligned)
    float* xv   = ws + 1536;      // 1024  x
    float* gh   = ws + 2560;      // 3072  gh (incl. b_hh)
    float* hn   = ws + 5632;      // 1024  h_new copy (16B aligned)
    float* pm   = ws + 6656;      // 1571  per-block max partials
    float* psum = ws + 8256;      // 1571  per-block sumexp partials

    float* out_logits = out;          // V
    float* out_hnew   = out + V;      // H
    float* out_attnw  = out + V + H;  // L

    k_phase1<<<1280, 256, 0, stream>>>(tok, hid, emb, Wa, ba, Whh, bhh, wlog, gh, aa);
    k_attn<<<32, 256, 0, stream>>>(wlog, enc, out_attnw, aa);
    k_comb<<<256, 256, 0, stream>>>(tok, emb, aa, Wc, bc, xv);
    k_gates_gru<<<256, 256, 0, stream>>>(xv, hid, Wih, bih, gh, out_hnew, hn);
    k_out_gemv<<<NB5, 256, 0, stream>>>(hn, Wo, bo, out_logits, pm, psum);
    k_finalize<<<197, 256, 0, stream>>>(out_logits, pm, psum);
}